// Round 3
// baseline (530.488 us; speedup 1.0000x reference)
//
#include <hip/hip_runtime.h>
#include <hip/hip_bf16.h>

typedef unsigned short u16;
typedef short s16x8 __attribute__((ext_vector_type(8)));
typedef float f32x4 __attribute__((ext_vector_type(4)));
typedef float f32x8 __attribute__((ext_vector_type(8)));
typedef u16 u16x8 __attribute__((ext_vector_type(8)));

#define DEV static __device__ __forceinline__

DEV float b2f(u16 u){ unsigned int i=((unsigned int)u)<<16; float f; __builtin_memcpy(&f,&i,4); return f; }
DEV u16 f2b(float x){ __hip_bfloat16 h=__float2bfloat16(x); u16 u; __builtin_memcpy(&u,&h,2); return u; }
DEV f32x4 MFMA(s16x8 a, s16x8 b, f32x4 c){ return __builtin_amdgcn_mfma_f32_16x16x32_bf16(a,b,c,0,0,0); }
DEV s16x8 LD8(const u16* p){ return *(const s16x8*)p; }
DEV s16x8 cvt8(const float* p){
  s16x8 r;
  #pragma unroll
  for (int i=0;i<8;i++) r[i] = (short)f2b(p[i]);
  return r;
}
DEV float geluf(float x){ return 0.5f*x*(1.0f+erff(x*0.70710678118654752f)); }
DEV float sigmf(float x){ return 1.0f/(1.0f+__expf(-x)); }

// ---------------- workspace layout (u16 elements) ----------------
#define WS_WeT   0
#define WS_W1T   65536
#define WS_W2T   327680
#define WS_WmT   589824
#define WS_WvT   655360
#define WS_WoT   917504
#define WS_WgoT  1048576
#define WS_nW1T  1572864
#define WS_nW2T  2621440
#define WS_SrcT  3670016
#define WS_TgtT  3801088
#define WS_GateT 3932160
#define WS_GgT   4063232
#define WS_NM    4587520
#define WS_TGT   5111808
#define WS_GP    5636096
#define WS_GG    6160384
#define WS_MSG   8257536
// U2 / X / Y alias the MSG region (MSG dead after k_attn)
#define WS_U2    8257536
#define WS_X     10354688   /* f32 region: 1,048,576 floats */
#define WS_Y     12451840
#define WS_WM    25034752
#define WS_U1    33423360
// total 33,947,648 u16 = 67.9 MB

// ---------------- transpose + bf16-cast all weights ----------------
struct P13 { const float* p[13]; };
__device__ const int TR_START[14] = {0,16,80,144,160,224,256,384,640,896,928,960,992,1120};
__device__ const int TR_R[13]   = {256,256,1024,256,256,256,1024,512,2048,512,512,512,512};
__device__ const int TR_C[13]   = {256,1024,256,256,1024,512,512,2048,512,256,256,256,1024};
__device__ const int TR_DST[13] = {WS_WeT,WS_W1T,WS_W2T,WS_WmT,WS_WvT,WS_WoT,WS_WgoT,
                                   WS_nW1T,WS_nW2T,WS_SrcT,WS_TgtT,WS_GateT,WS_GgT};

__global__ __launch_bounds__(256) void k_transpose(P13 ps, u16* __restrict__ ws){
  __shared__ alignas(16) u16 Ts[64][72];
  const int t = threadIdx.x;
  int bid = blockIdx.x;
  int mi = 0;
  #pragma unroll 1
  while (bid >= TR_START[mi+1]) ++mi;
  const float* src = ps.p[mi];
  const int R = TR_R[mi], C = TR_C[mi];
  u16* dst = ws + TR_DST[mi];
  const int ti = bid - TR_START[mi];
  const int tcn = C >> 6;
  const int tr = ti / tcn, tc = ti % tcn;
  {
    const int row = t >> 2, cs = (t & 3) * 16;
    const float* sp = src + (tr*64 + row)*C + tc*64 + cs;
    u16x8 a, b;
    #pragma unroll
    for (int i=0;i<8;i++){ a[i]=f2b(sp[i]); b[i]=f2b(sp[8+i]); }
    *(u16x8*)&Ts[row][cs]   = a;
    *(u16x8*)&Ts[row][cs+8] = b;
  }
  __syncthreads();
  {
    const int col = t >> 2, rs = (t & 3) * 16;
    u16x8 a, b;
    #pragma unroll
    for (int i=0;i<8;i++){ a[i]=Ts[rs+i][col]; b[i]=Ts[rs+8+i][col]; }
    u16* dp = dst + (tc*64 + col)*R + tr*64 + rs;
    *(u16x8*)dp = a;
    *(u16x8*)(dp+8) = b;
  }
}

// ---------------- k_proj: node projections + gates ----------------
// grid (32, 28): y 0-3 node_msg | 4-7 tgt | 8-11 pool gate | 12-27 gat gate
__global__ __launch_bounds__(256) void k_proj(const float* __restrict__ node_repr,
                                              const float* __restrict__ bgate,
                                              const float* __restrict__ bgg,
                                              u16* __restrict__ ws){
  const int t=threadIdx.x, lid=t&63, w=t>>6, g=lid>>4, q=lid&15;
  const int rb = blockIdx.x, yb = blockIdx.y;
  const u16* BT; u16* dst; int Nseg, colbase, act=0; const float* bias=nullptr;
  if (yb < 4){ BT=ws+WS_SrcT;  dst=ws+WS_NM; Nseg=256;  colbase=yb*64; }
  else if (yb < 8){ BT=ws+WS_TgtT;  dst=ws+WS_TGT; Nseg=256; colbase=(yb-4)*64; }
  else if (yb < 12){ BT=ws+WS_GateT; dst=ws+WS_GP; Nseg=256; colbase=(yb-8)*64; act=1; bias=bgate; }
  else { BT=ws+WS_GgT; dst=ws+WS_GG; Nseg=1024; colbase=(yb-12)*64; act=1; bias=bgg; }
  const int wr=(w>>1)*32, wcl=(w&1)*32;
  f32x4 acc[2][2] = {};
  for (int kk=0; kk<512; kk+=32){
    s16x8 af[2], bfr[2];
    #pragma unroll
    for (int i=0;i<2;i++) af[i] = cvt8(node_repr + (rb*64 + wr + i*16 + q)*512 + kk + 8*g);
    #pragma unroll
    for (int j=0;j<2;j++) bfr[j] = LD8(BT + (colbase + wcl + j*16 + q)*512 + kk + 8*g);
    #pragma unroll
    for (int i=0;i<2;i++)
      #pragma unroll
      for (int j=0;j<2;j++) acc[i][j] = MFMA(af[i], bfr[j], acc[i][j]);
  }
  #pragma unroll
  for (int i=0;i<2;i++)
    #pragma unroll
    for (int j=0;j<2;j++)
      #pragma unroll
      for (int r=0;r<4;r++){
        const int row = rb*64 + wr + i*16 + g*4 + r;
        const int col = wcl + j*16 + q;
        float v = acc[i][j][r];
        if (act) v = sigmf(v + bias[colbase+col]);
        dst[row*Nseg + colbase + col] = f2b(v);
      }
}

// ---------------- k_edge: pre + LN + MLP + mask -> MSG ----------------
__global__ __launch_bounds__(256) void k_edge(
    const float* __restrict__ edge_repr, const int* __restrict__ edge_index,
    const int* __restrict__ edge_mask, const float* __restrict__ mask_bw,
    const float* __restrict__ ln_g, const float* __restrict__ ln_b,
    const float* __restrict__ b1v, const float* __restrict__ b2v,
    u16* __restrict__ ws)
{
  __shared__ alignas(16) u16 Y[64][256];
  __shared__ alignas(16) u16 Hc[64][128];
  __shared__ float rsS[4][64], rsQ[4][64];
  __shared__ int idxL[64]; __shared__ int emL[64]; __shared__ float mbwL[64];

  const int t=threadIdx.x, lid=t&63, w=t>>6, g=lid>>4, q=lid&15;
  const int R0 = blockIdx.x * 64;
  const int wc = w * 64;

  if (t < 64){
    idxL[t] = edge_index[R0+t];
    emL[t]  = edge_mask[R0+t];
    mbwL[t] = mask_bw[R0+t];
  }
  __syncthreads();

  // acc init: gather*mbw + tgt
  const u16* nm = ws + WS_NM;
  const u16* tg = ws + WS_TGT;
  f32x4 acc[4][4];
  #pragma unroll
  for (int i=0;i<4;i++)
    #pragma unroll
    for (int r=0;r<4;r++){
      const int row = i*16 + g*4 + r;
      const int er  = R0 + row;
      const int gnd = er >> 5;
      const int bi  = gnd >> 10;
      const int srow = bi*1024 + idxL[row];
      const float mb = mbwL[row];
      #pragma unroll
      for (int j=0;j<4;j++){
        const int col = wc + j*16 + q;
        acc[i][j][r] = b2f(nm[srow*256 + col])*mb + b2f(tg[gnd*256 + col]);
      }
    }
  // pre-GEMM: + edge_repr @ We
  for (int kk=0; kk<256; kk+=32){
    s16x8 af[4], bfr[4];
    #pragma unroll
    for (int i=0;i<4;i++) af[i] = cvt8(edge_repr + (R0 + i*16 + q)*256 + kk + 8*g);
    #pragma unroll
    for (int j=0;j<4;j++) bfr[j] = LD8(ws + WS_WeT + (wc + j*16 + q)*256 + kk + 8*g);
    #pragma unroll
    for (int i=0;i<4;i++)
      #pragma unroll
      for (int j=0;j<4;j++) acc[i][j] = MFMA(af[i], bfr[j], acc[i][j]);
  }
  // LayerNorm over 256 (cross-wave via LDS partials)
  #pragma unroll
  for (int i=0;i<4;i++)
    #pragma unroll
    for (int r=0;r<4;r++){
      float s=0.f, s2=0.f;
      #pragma unroll
      for (int j=0;j<4;j++){ float v=acc[i][j][r]; s+=v; s2+=v*v; }
      #pragma unroll
      for (int m=1;m<16;m<<=1){ s += __shfl_xor(s,m,64); s2 += __shfl_xor(s2,m,64); }
      if (q==0){ const int row=i*16+g*4+r; rsS[w][row]=s; rsQ[w][row]=s2; }
    }
  __syncthreads();
  #pragma unroll
  for (int i=0;i<4;i++)
    #pragma unroll
    for (int r=0;r<4;r++){
      const int row=i*16+g*4+r;
      const float s  = rsS[0][row]+rsS[1][row]+rsS[2][row]+rsS[3][row];
      const float s2 = rsQ[0][row]+rsQ[1][row]+rsQ[2][row]+rsQ[3][row];
      const float mean = s*(1.f/256.f);
      const float var  = s2*(1.f/256.f) - mean*mean;
      const float rstd = rsqrtf(var + 1e-5f);
      #pragma unroll
      for (int j=0;j<4;j++){
        const int col = wc + j*16 + q;
        Y[row][col] = f2b((acc[i][j][r]-mean)*rstd*ln_g[col] + ln_b[col]);
      }
    }
  __syncthreads();

  // MLP 256 -> 1024 (gelu) -> 256, hidden in chunks of 128
  f32x4 oacc[4][4] = {};
  for (int c=0;c<8;c++){
    f32x4 hacc[4][2] = {};
    for (int kk=0;kk<256;kk+=32){
      s16x8 af[4], bfr[2];
      #pragma unroll
      for (int i=0;i<4;i++) af[i] = LD8(&Y[i*16+q][kk+8*g]);
      #pragma unroll
      for (int j=0;j<2;j++) bfr[j] = LD8(ws + WS_W1T + (c*128 + w*32 + j*16 + q)*256 + kk + 8*g);
      #pragma unroll
      for (int i=0;i<4;i++)
        #pragma unroll
        for (int j=0;j<2;j++) hacc[i][j] = MFMA(af[i], bfr[j], hacc[i][j]);
    }
    __syncthreads();   // prior-chunk Hc reads done
    #pragma unroll
    for (int i=0;i<4;i++)
      #pragma unroll
      for (int j=0;j<2;j++)
        #pragma unroll
        for (int r=0;r<4;r++){
          const int row = i*16 + g*4 + r;
          const int hcol = w*32 + j*16 + q;
          Hc[row][hcol] = f2b(geluf(hacc[i][j][r] + b1v[c*128 + hcol]));
        }
    __syncthreads();
    for (int kk=0;kk<128;kk+=32){
      s16x8 af[4], bfr[4];
      #pragma unroll
      for (int i=0;i<4;i++) af[i] = LD8(&Hc[i*16+q][kk+8*g]);
      #pragma unroll
      for (int j=0;j<4;j++) bfr[j] = LD8(ws + WS_W2T + (wc + j*16 + q)*1024 + c*128 + kk + 8*g);
      #pragma unroll
      for (int i=0;i<4;i++)
        #pragma unroll
        for (int j=0;j<4;j++) oacc[i][j] = MFMA(af[i], bfr[j], oacc[i][j]);
    }
  }
  // epilogue: +b2, mask, store MSG
  u16* msg = ws + WS_MSG;
  #pragma unroll
  for (int i=0;i<4;i++)
    #pragma unroll
    for (int j=0;j<4;j++)
      #pragma unroll
      for (int r=0;r<4;r++){
        const int row=i*16+g*4+r, col=wc+j*16+q;
        float v = oacc[i][j][r] + b2v[col];
        if (!emL[row]) v = 0.f;
        msg[(R0+row)*256 + col] = f2b(v);
      }
}

// ---------------- k_attn: lrelu-GEMM, attn bias, softmax, wm, pool ----------------
__global__ __launch_bounds__(256) void k_attn(const int* __restrict__ edge_mask,
                                              const float* __restrict__ wab,
                                              u16* __restrict__ ws){
  __shared__ alignas(16) u16 Tm[32][256];
  __shared__ alignas(16) u16 WabT[16][256];
  __shared__ alignas(16) u16 PT[16][32];
  __shared__ alignas(16) u16 MsgT[256][32];
  __shared__ float Pp[4][32][16];
  __shared__ int emL[32];
  __shared__ float cntS;

  const int t=threadIdx.x, lid=t&63, w=t>>6, g=lid>>4, q=lid&15;
  const int nd = blockIdx.x;
  const int wc = w*64;
  const u16* msg = ws + WS_MSG + nd*32*256;

  if (t < 32) emL[t] = edge_mask[nd*32 + t];
  __syncthreads();
  if (t == 0){ float c=0.f; for (int k=0;k<32;k++) c += emL[k]?1.f:0.f; cntS=c; }

  // Tm = lrelu(msg @ Wm)
  f32x4 ta[2][4] = {};
  for (int kk=0;kk<256;kk+=32){
    s16x8 af[2], bfr[4];
    #pragma unroll
    for (int i=0;i<2;i++) af[i] = LD8(msg + (i*16+q)*256 + kk + 8*g);
    #pragma unroll
    for (int j=0;j<4;j++) bfr[j] = LD8(ws + WS_WmT + (wc + j*16 + q)*256 + kk + 8*g);
    #pragma unroll
    for (int i=0;i<2;i++)
      #pragma unroll
      for (int j=0;j<4;j++) ta[i][j] = MFMA(af[i], bfr[j], ta[i][j]);
  }
  #pragma unroll
  for (int i=0;i<2;i++)
    #pragma unroll
    for (int j=0;j<4;j++)
      #pragma unroll
      for (int r=0;r<4;r++){
        const int row=i*16+g*4+r, col=wc+j*16+q;
        float v = ta[i][j][r];
        Tm[row][col] = f2b(v > 0.f ? v : 0.01f*v);
      }
  // WabT[h][k] = wab[k][h]
  {
    #pragma unroll
    for (int h=0;h<16;h++) WabT[h][t] = f2b(wab[t*16 + h]);
  }
  __syncthreads();
  // ab partials: wave w covers K range [w*64, w*64+64)
  {
    f32x4 aa[2] = {};
    #pragma unroll
    for (int s2=0;s2<2;s2++){
      const int kk = w*64 + s2*32;
      s16x8 bfr = LD8(&WabT[q][kk + 8*g]);
      #pragma unroll
      for (int i=0;i<2;i++){
        s16x8 af = LD8(&Tm[i*16+q][kk + 8*g]);
        aa[i] = MFMA(af, bfr, aa[i]);
      }
    }
    #pragma unroll
    for (int i=0;i<2;i++)
      #pragma unroll
      for (int r=0;r<4;r++) Pp[w][i*16+g*4+r][q] = aa[i][r];
  }
  __syncthreads();
  for (int e=t; e<512; e+=256){
    const int k=e>>4, h=e&15;
    float v = Pp[0][k][h]+Pp[1][k][h]+Pp[2][k][h]+Pp[3][k][h];
    Pp[0][k][h] = emL[k] ? v : -3.4028235e38f;
  }
  __syncthreads();
  // MsgT[c][k] = msg[k][c]
  {
    const int c = t;
    #pragma unroll 1
    for (int k=0;k<32;k++) MsgT[c][k] = msg[k*256 + c];
  }
  // softmax over k per head
  if (t < 16){
    const int h = t;
    float m = -3.4028235e38f;
    for (int k=0;k<32;k++) m = fmaxf(m, Pp[0][k][h]);
    float s = 0.f;
    float ev[32];
    for (int k=0;k<32;k++){ ev[k]=__expf(Pp[0][k][h]-m); s+=ev[k]; }
    const float inv = 1.f/s;
    for (int k=0;k<32;k++) PT[h][k] = f2b(ev[k]*inv);
  }
  __syncthreads();
  // wm[h][:] = attn^T @ msg   (K=32, single k-step)
  {
    s16x8 pa = LD8(&PT[q][8*g]);
    f32x4 wmac[4] = {};
    #pragma unroll
    for (int j=0;j<4;j++){
      s16x8 mb = LD8(&MsgT[wc + j*16 + q][8*g]);
      wmac[j] = MFMA(pa, mb, wmac[j]);
    }
    u16* wmw = ws + WS_WM;
    #pragma unroll
    for (int j=0;j<4;j++)
      #pragma unroll
      for (int r=0;r<4;r++){
        const int hh = g*4 + r;
        const int col = wc + j*16 + q;
        wmw[hh*(2048*256) + nd*256 + col] = f2b(wmac[j][r]);
      }
  }
  // pooled o * gate -> U1
  {
    const int c = t;
    float s = 0.f;
    #pragma unroll 1
    for (int k=0;k<32;k++) s += b2f(msg[k*256 + c]);
    const float o = s / (cntS + 1e-6f);
    ws[WS_U1 + nd*256 + c] = f2b(o * b2f(ws[WS_GP + nd*256 + c]));
  }
}

// ---------------- k_og: per-head value GEMM + gate -> U2 ----------------
__global__ __launch_bounds__(256) void k_og(u16* __restrict__ ws){
  const int t=threadIdx.x, lid=t&63, w=t>>6, g=lid>>4, q=lid&15;
  const int rb=blockIdx.x, h=blockIdx.y;
  const int wr=(w>>1)*32, wcl=(w&1)*32;
  const u16* A  = ws + WS_WM  + h*(2048*256);
  const u16* BT = ws + WS_WvT;
  f32x4 acc[2][2] = {};
  for (int kk=0;kk<256;kk+=32){
    s16x8 af[2], bfr[2];
    #pragma unroll
    for (int i=0;i<2;i++) af[i] = LD8(A + (rb*64 + wr + i*16 + q)*256 + kk + 8*g);
    #pragma unroll
    for (int j=0;j<2;j++) bfr[j] = LD8(BT + (h*64 + wcl + j*16 + q)*256 + kk + 8*g);
    #pragma unroll
    for (int i=0;i<2;i++)
      #pragma unroll
      for (int j=0;j<2;j++) acc[i][j] = MFMA(af[i], bfr[j], acc[i][j]);
  }
  #pragma unroll
  for (int i=0;i<2;i++)
    #pragma unroll
    for (int j=0;j<2;j++)
      #pragma unroll
      for (int r=0;r<4;r++){
        const int row = rb*64 + wr + i*16 + g*4 + r;
        const int col = h*64 + wcl + j*16 + q;
        const float gv = b2f(ws[WS_GG + row*1024 + col]);
        ws[WS_U2 + row*1024 + col] = f2b(acc[i][j][r] * gv);
      }
}

// ---------------- k_dh: dh = u1@Wo + u2@Wgo ; X = node_repr + dh (f32) ----------------
__global__ __launch_bounds__(256) void k_dh(const float* __restrict__ node_repr, u16* __restrict__ ws){
  const int t=threadIdx.x, lid=t&63, w=t>>6, g=lid>>4, q=lid&15;
  const int rb=blockIdx.x, cb=blockIdx.y*64;
  const int wr=(w>>1)*32, wcl=(w&1)*32;
  float* Xf = (float*)(ws + WS_X);
  f32x4 acc[2][2] = {};
  for (int kk=0;kk<256;kk+=32){
    s16x8 af[2], bfr[2];
    #pragma unroll
    for (int i=0;i<2;i++) af[i] = LD8(ws + WS_U1 + (rb*64 + wr + i*16 + q)*256 + kk + 8*g);
    #pragma unroll
    for (int j=0;j<2;j++) bfr[j] = LD8(ws + WS_WoT + (cb + wcl + j*16 + q)*256 + kk + 8*g);
    #pragma unroll
    for (int i=0;i<2;i++)
      #pragma unroll
      for (int j=0;j<2;j++) acc[i][j] = MFMA(af[i], bfr[j], acc[i][j]);
  }
  for (int kk=0;kk<1024;kk+=32){
    s16x8 af[2], bfr[2];
    #pragma unroll
    for (int i=0;i<2;i++) af[i] = LD8(ws + WS_U2 + (rb*64 + wr + i*16 + q)*1024 + kk + 8*g);
    #pragma unroll
    for (int j=0;j<2;j++) bfr[j] = LD8(ws + WS_WgoT + (cb + wcl + j*16 + q)*1024 + kk + 8*g);
    #pragma unroll
    for (int i=0;i<2;i++)
      #pragma unroll
      for (int j=0;j<2;j++) acc[i][j] = MFMA(af[i], bfr[j], acc[i][j]);
  }
  #pragma unroll
  for (int i=0;i<2;i++)
    #pragma unroll
    for (int j=0;j<2;j++)
      #pragma unroll
      for (int r=0;r<4;r++){
        const int row = rb*64 + wr + i*16 + g*4 + r;
        const int col = cb + wcl + j*16 + q;
        Xf[row*512 + col] = acc[i][j][r] + node_repr[row*512 + col];
      }
}

// ---------------- k_ln512: Y = LN(X)*g + b (bf16 out) ----------------
__global__ __launch_bounds__(256) void k_ln512(const float* __restrict__ g_, const float* __restrict__ b_,
                                               u16* __restrict__ ws){
  const int t=threadIdx.x, wid=t>>6, lane=t&63;
  const int row = blockIdx.x*4 + wid;
  const float* xr = (const float*)(ws + WS_X) + row*512;
  f32x8 xv = *(const f32x8*)(xr + lane*8);
  float s=0.f, s2=0.f;
  #pragma unroll
  for (int i=0;i<8;i++){ s+=xv[i]; s2+=xv[i]*xv[i]; }
  #pragma unroll
  for (int m=1;m<64;m<<=1){ s += __shfl_xor(s,m,64); s2 += __shfl_xor(s2,m,64); }
  const float mean = s*(1.f/512.f);
  const float var  = s2*(1.f/512.f) - mean*mean;
  const float rstd = rsqrtf(var + 1e-5f);
  u16x8 yv;
  #pragma unroll
  for (int i=0;i<8;i++) yv[i] = f2b((xv[i]-mean)*rstd*g_[lane*8+i] + b_[lane*8+i]);
  *(u16x8*)(ws + WS_Y + row*512 + lane*8) = yv;
}

// ---------------- k_nodemlp: out = X + MLP(Y) (f32 out) ----------------
__global__ __launch_bounds__(256) void k_nodemlp(const float* __restrict__ nb1, const float* __restrict__ nb2,
                                                 float* __restrict__ out, u16* __restrict__ ws){
  __shared__ alignas(16) u16 Hc[32][128];
  const int t=threadIdx.x, lid=t&63, w=t>>6, g=lid>>4, q=lid&15;
  const int R0 = blockIdx.x * 32;
  const u16* Yg = ws + WS_Y;
  const float* Xf = (const float*)(ws + WS_X);
  f32x4 oacc[2][8] = {};
  for (int c=0;c<16;c++){
    f32x4 hacc[2][2] = {};
    for (int kk=0;kk<512;kk+=32){
      s16x8 af[2], bfr[2];
      #pragma unroll
      for (int i=0;i<2;i++) af[i] = LD8(Yg + (R0 + i*16 + q)*512 + kk + 8*g);
      #pragma unroll
      for (int j=0;j<2;j++) bfr[j] = LD8(ws + WS_nW1T + (c*128 + w*32 + j*16 + q)*512 + kk + 8*g);
      #pragma unroll
      for (int i=0;i<2;i++)
        #pragma unroll
        for (int j=0;j<2;j++) hacc[i][j] = MFMA(af[i], bfr[j], hacc[i][j]);
    }
    __syncthreads();
    #pragma unroll
    for (int i=0;i<2;i++)
      #pragma unroll
      for (int j=0;j<2;j++)
        #pragma unroll
        for (int r=0;r<4;r++){
          const int row = i*16 + g*4 + r;
          const int hcol = w*32 + j*16 + q;
          Hc[row][hcol] = f2b(geluf(hacc[i][j][r] + nb1[c*128 + hcol]));
        }
    __syncthreads();
    for (int kk=0;kk<128;kk+=32){
      s16x8 af[2], bfr[8];
      #pragma unroll
      for (int i=0;i<2;i++) af[i] = LD8(&Hc[i*16+q][kk+8*g]);
      #pragma unroll
      for (int j=0;j<8;j++) bfr[j] = LD8(ws + WS_nW2T + (w*128 + j*16 + q)*2048 + c*128 + kk + 8*g);
      #pragma unroll
      for (int i=0;i<2;i++)
        #pragma unroll
        for (int j=0;j<8;j++) oacc[i][j] = MFMA(af[i], bfr[j], oacc[i][j]);
    }
  }
  #pragma unroll
  for (int i=0;i<2;i++)
    #pragma unroll
    for (int j=0;j<8;j++)
      #pragma unroll
      for (int r=0;r<4;r++){
        const int row = i*16 + g*4 + r;
        const int col = w*128 + j*16 + q;
        out[(R0+row)*512 + col] = oacc[i][j][r] + nb2[col] + Xf[(R0+row)*512 + col];
      }
}

extern "C" void kernel_launch(void* const* d_in, const int* in_sizes, int n_in,
                              void* d_out, int out_size, void* d_ws, size_t ws_size,
                              hipStream_t stream){
  (void)in_sizes; (void)n_in; (void)out_size; (void)ws_size;
  const float* node_repr = (const float*)d_in[0];
  const float* edge_repr = (const float*)d_in[1];
  const int* edge_index = (const int*)d_in[2];
  const int* edge_mask  = (const int*)d_in[3];
  const float* mask_bw = (const float*)d_in[4];
  u16* ws = (u16*)d_ws;

  P13 ps;
  const int srcIdx[13] = {5,10,12,17,19,16,22,25,27,6,7,14,20};
  for (int i=0;i<13;i++) ps.p[i] = (const float*)d_in[srcIdx[i]];

  hipLaunchKernelGGL(k_transpose, dim3(1120), dim3(256), 0, stream, ps, ws);
  hipLaunchKernelGGL(k_proj, dim3(32,28), dim3(256), 0, stream,
                     node_repr, (const float*)d_in[15], (const float*)d_in[21], ws);
  hipLaunchKernelGGL(k_edge, dim3(1024), dim3(256), 0, stream,
                     edge_repr, edge_index, edge_mask, mask_bw,
                     (const float*)d_in[8], (const float*)d_in[9],
                     (const float*)d_in[11], (const float*)d_in[13], ws);
  hipLaunchKernelGGL(k_attn, dim3(2048), dim3(256), 0, stream,
                     edge_mask, (const float*)d_in[18], ws);
  hipLaunchKernelGGL(k_og, dim3(32,16), dim3(256), 0, stream, ws);
  hipLaunchKernelGGL(k_dh, dim3(32,8), dim3(256), 0, stream, node_repr, ws);
  hipLaunchKernelGGL(k_ln512, dim3(512), dim3(256), 0, stream,
                     (const float*)d_in[23], (const float*)d_in[24], ws);
  hipLaunchKernelGGL(k_nodemlp, dim3(64), dim3(256), 0, stream,
                     (const float*)d_in[26], (const float*)d_in[28], (float*)d_out, ws);
}